// Round 1
// baseline (330.712 us; speedup 1.0000x reference)
//
#include <hip/hip_runtime.h>

#define BLOCK 256

__global__ __launch_bounds__(BLOCK, 2)
void poi_fused_kernel(const float* __restrict__ poi,
                      const float* __restrict__ tin,
                      const float* __restrict__ wm,
                      const float* __restrict__ bm,
                      const float* __restrict__ wf,
                      const float* __restrict__ bf,
                      const float* __restrict__ wc,
                      const float* __restrict__ bc,
                      float* __restrict__ out)
{
    constexpr int HW = 64 * 64;       // 4096 pixels per batch image
    constexpr int CP = 128;           // poi channels
    constexpr int CT = 31;            // time channels
    constexpr int CZ = 32;            // hidden channels
    constexpr int CO = 64;            // output channels

    __shared__ float s_wc[CO * CP];   // 32 KiB, rows of 128 (16B-aligned)
    __shared__ float s_wm[CZ * 32];   // rows padded 31 -> 32 (16B-aligned)
    __shared__ float s_wf[CZ];
    __shared__ float s_bm[CZ];
    __shared__ float s_bc[CO];
    __shared__ float s_bf;

    const int tid = threadIdx.x;

    // ---- cooperative weight staging (coalesced) ----
    for (int i = tid; i < CO * CP; i += BLOCK) s_wc[i] = wc[i];
    for (int i = tid; i < CZ * 32; i += BLOCK) {
        const int k = i >> 5, c = i & 31;
        s_wm[i] = (c < CT) ? wm[k * CT + c] : 0.0f;
    }
    if (tid < CZ) { s_wf[tid] = wf[tid]; s_bm[tid] = bm[tid]; }
    if (tid < CO) s_bc[tid] = bc[tid];
    if (tid == 0) s_bf = bf[0];
    __syncthreads();

    const int b   = blockIdx.x >> 4;                 // 4096/256 = 16 blocks per batch
    const int pix = ((blockIdx.x & 15) << 8) + tid;  // pixel within the image

    // ---- stage 1: t = relu( wf . relu(wm @ time + bm) + bf ) ----
    float tr[32];
    {
        const float* tp = tin + (size_t)b * CT * HW + pix;
        #pragma unroll
        for (int c = 0; c < CT; ++c) tr[c] = tp[c * HW];   // coalesced across lanes
        tr[31] = 0.0f;                                     // pad so rows are 32-wide
    }
    float tacc = s_bf;
    #pragma unroll
    for (int k = 0; k < CZ; ++k) {
        float z = s_bm[k];
        #pragma unroll
        for (int q = 0; q < 8; ++q) {
            // wave-uniform address -> LDS broadcast, no bank conflicts
            const float4 w = *reinterpret_cast<const float4*>(&s_wm[k * 32 + q * 4]);
            z = fmaf(w.x, tr[4 * q + 0], z);
            z = fmaf(w.y, tr[4 * q + 1], z);
            z = fmaf(w.z, tr[4 * q + 2], z);
            z = fmaf(w.w, tr[4 * q + 3], z);
        }
        z = fmaxf(z, 0.0f);
        tacc = fmaf(s_wf[k], z, tacc);
    }
    const float t = fmaxf(tacc, 0.0f);

    // ---- stage 2: out[o] = t * (wc[o,:] . poi[:,pix]) + bc[o] ----
    float acc[CO];
    #pragma unroll
    for (int o = 0; o < CO; ++o) acc[o] = 0.0f;

    const float* pp = poi + (size_t)b * CP * HW + pix;
    #pragma unroll 2
    for (int c = 0; c < CP; c += 4) {
        const float p0 = pp[(size_t)(c + 0) * HW];
        const float p1 = pp[(size_t)(c + 1) * HW];
        const float p2 = pp[(size_t)(c + 2) * HW];
        const float p3 = pp[(size_t)(c + 3) * HW];
        #pragma unroll
        for (int o = 0; o < CO; ++o) {
            const float4 w = *reinterpret_cast<const float4*>(&s_wc[o * CP + c]);
            float a = acc[o];
            a = fmaf(w.x, p0, a);
            a = fmaf(w.y, p1, a);
            a = fmaf(w.z, p2, a);
            a = fmaf(w.w, p3, a);
            acc[o] = a;
        }
    }

    float* op = out + (size_t)b * CO * HW + pix;
    #pragma unroll
    for (int o = 0; o < CO; ++o)
        op[(size_t)o * HW] = fmaf(t, acc[o], s_bc[o]);
}

extern "C" void kernel_launch(void* const* d_in, const int* in_sizes, int n_in,
                              void* d_out, int out_size, void* d_ws, size_t ws_size,
                              hipStream_t stream) {
    const float* poi = (const float*)d_in[0];
    const float* tin = (const float*)d_in[1];
    const float* wm  = (const float*)d_in[2];
    const float* bm  = (const float*)d_in[3];
    const float* wf  = (const float*)d_in[4];
    const float* bf  = (const float*)d_in[5];
    const float* wc  = (const float*)d_in[6];
    const float* bc  = (const float*)d_in[7];
    float* out = (float*)d_out;

    // B=32, 16 blocks of 256 pixels per image
    dim3 grid(32 * 16), block(BLOCK);
    hipLaunchKernelGGL(poi_fused_kernel, grid, block, 0, stream,
                       poi, tin, wm, bm, wf, bf, wc, bc, out);
}

// Round 2
// 54.783 us; speedup vs baseline: 6.0368x; 6.0368x over previous
//
#include <hip/hip_runtime.h>

constexpr int HW = 4096;   // 64*64
constexpr int CT = 31;     // time channels
constexpr int CZ = 32;     // hidden channels
constexpr int CP = 128;    // poi channels
constexpr int CO = 64;     // output channels

// ---------------- kernel 1: per-pixel time MLP -> t[b*HW + pix] ----------------
__global__ __launch_bounds__(256)
void time_mlp_kernel(const float* __restrict__ tin,
                     const float* __restrict__ wm,
                     const float* __restrict__ bm,
                     const float* __restrict__ wf,
                     const float* __restrict__ bf,
                     float* __restrict__ tout)
{
    const int gid = blockIdx.x * 256 + threadIdx.x;           // 131072 threads
    const float* tp = tin + (size_t)(gid >> 12) * CT * HW + (gid & (HW - 1));

    float tr[CT];
    #pragma unroll
    for (int c = 0; c < CT; ++c) tr[c] = tp[(size_t)c * HW];  // coalesced

    float acc = bf[0];
    #pragma unroll
    for (int k = 0; k < CZ; ++k) {
        float z = bm[k];                                      // uniform -> s_load
        #pragma unroll
        for (int c = 0; c < CT; ++c)
            z = fmaf(wm[k * CT + c], tr[c], z);               // uniform -> s_load
        acc = fmaf(wf[k], fmaxf(z, 0.f), acc);
    }
    tout[gid] = fmaxf(acc, 0.f);
}

// ------------- kernel 2: out[b,o,p] = t[b,p] * (wc[o,:].poi[b,:,p]) + bc[o] -------------
// block = 256 threads = 4 waves; wave w owns output channels [16w, 16w+16)
// lanes cover 128 consecutive pixels, 2 px/lane; grid = B * (HW/128) blocks.
__global__ __launch_bounds__(256)
void poi_gemm_kernel(const float* __restrict__ poi,
                     const float* __restrict__ t,
                     const float* __restrict__ wc,
                     const float* __restrict__ bc,
                     float* __restrict__ out)
{
    const int lane = threadIdx.x & 63;
    const int og   = __builtin_amdgcn_readfirstlane(threadIdx.x >> 6) * 16; // SGPR
    const int b    = blockIdx.x >> 5;                          // 32 px-tiles per image
    const int px0  = ((blockIdx.x & 31) << 7) + (lane << 1);   // 2 consecutive pixels

    const float* pp = poi + (size_t)b * CP * HW + px0;
    const float* wg = wc + (size_t)og * CP;                    // uniform base

    float accx[16], accy[16];
    #pragma unroll
    for (int o = 0; o < 16; ++o) { accx[o] = 0.f; accy[o] = 0.f; }

    #pragma unroll 2
    for (int c = 0; c < CP; c += 4) {
        float2 p[4];
        #pragma unroll
        for (int q = 0; q < 4; ++q)
            p[q] = *reinterpret_cast<const float2*>(pp + (size_t)(c + q) * HW);
        #pragma unroll
        for (int o = 0; o < 16; ++o) {
            #pragma unroll
            for (int q = 0; q < 4; ++q) {
                const float w = wg[o * CP + c + q];            // uniform -> s_load
                accx[o] = fmaf(w, p[q].x, accx[o]);
                accy[o] = fmaf(w, p[q].y, accy[o]);
            }
        }
    }

    const float2 tv = *reinterpret_cast<const float2*>(t + (size_t)b * HW + px0);

    float* op = out + (size_t)b * CO * HW + (size_t)og * HW + px0;
    #pragma unroll
    for (int o = 0; o < 16; ++o) {
        float2 r;
        const float bias = bc[og + o];                         // uniform -> s_load
        r.x = fmaf(tv.x, accx[o], bias);
        r.y = fmaf(tv.y, accy[o], bias);
        *reinterpret_cast<float2*>(op + (size_t)o * HW) = r;
    }
}

extern "C" void kernel_launch(void* const* d_in, const int* in_sizes, int n_in,
                              void* d_out, int out_size, void* d_ws, size_t ws_size,
                              hipStream_t stream) {
    const float* poi = (const float*)d_in[0];
    const float* tin = (const float*)d_in[1];
    const float* wm  = (const float*)d_in[2];
    const float* bm  = (const float*)d_in[3];
    const float* wf  = (const float*)d_in[4];
    const float* bf  = (const float*)d_in[5];
    const float* wc  = (const float*)d_in[6];
    const float* bc  = (const float*)d_in[7];
    float* out = (float*)d_out;
    float* tbuf = (float*)d_ws;                    // 131072 floats = 512 KiB

    hipLaunchKernelGGL(time_mlp_kernel, dim3(512), dim3(256), 0, stream,
                       tin, wm, bm, wf, bf, tbuf);
    hipLaunchKernelGGL(poi_gemm_kernel, dim3(32 * 32), dim3(256), 0, stream,
                       poi, tbuf, wc, bc, out);
}